// Round 4
// baseline (70.027 us; speedup 1.0000x reference)
//
#include <hip/hip_runtime.h>
#include <math.h>

#define NG 1024
#define HH 256
#define WW 256
#define TILE_PX 64
#define WT 4
#define FOCAL_F 256.0f      // W / (2 * TAN_FOV)
#define RADII_MULT_F 5.0f

// Single fused kernel: 512 blocks = 16 tiles x 32 row-pairs, 4 waves/block.
// Waves = 2 rows x 2 list-halves. Each block projects all 1024 gaussians
// (4/thread), compacts the ones overlapping its 64x2 window, ranks survivors
// by stable depth key, then each wave blends HALF the sorted list for its row
// (alpha compositing is associative: c = c_f + T_f*c_b, T = T_f*T_b).
__global__ __launch_bounds__(256) void fused_render_kernel(
    const float* __restrict__ means3d, const float* __restrict__ opacity,
    const float* __restrict__ scale3d, const float* __restrict__ features,
    const float* __restrict__ viewm, const float* __restrict__ projm,
    float* __restrict__ out)
{
    __shared__ float4 s_sorted[NG][2];            // 32 KB: (attrA, attrB) at ranked pos
    __shared__ unsigned long long s_key[NG];      // 8 KB: compacted keys, 4 segments
    __shared__ float s_part[2][5][64];            // back-half partials per row/lane
    __shared__ int s_cnt[4];

    const int blk  = blockIdx.x;                  // 512 blocks
    const int tile = blk >> 5;                    // 16 tiles
    const int rg   = blk & 31;                    // row-pair within tile
    const int u0 = (tile & (WT - 1)) * TILE_PX;
    const int v0 = (tile / WT) * TILE_PX;
    const int t = threadIdx.x;
    const int l = t & 63;
    const int w = t >> 6;
    const int row  = w >> 1;                      // 0..1 within pair
    const int half = w & 1;                       // 0 = front of list, 1 = back

    const int pxi = u0 + l;
    const int pyi = v0 + rg * 2 + row;
    const float px = (float)pxi;
    const float py = (float)pyi;
    const float u0f  = (float)u0;
    const float u1f  = (float)(u0 + TILE_PX - 1);
    const float py0f = (float)(v0 + rg * 2);
    const float py1f = py0f + 1.0f;

    // matrices (broadcast scalar loads)
    float V[16], P[16];
#pragma unroll
    for (int j = 0; j < 16; j++) { V[j] = viewm[j]; P[j] = projm[j]; }

    // ---- raw inputs for my 4 gaussians (g = k*256 + t), coalesced ----
    float mx[4], my[4], mz[4], sc[4], op[4], fr[4], fg[4], fb[4];
#pragma unroll
    for (int k = 0; k < 4; k++) {
        const int g = (k << 8) + t;
        mx[k] = means3d[g * 3 + 0];
        my[k] = means3d[g * 3 + 1];
        mz[k] = means3d[g * 3 + 2];
        sc[k] = scale3d[g];
        op[k] = opacity[g];
        fr[k] = features[g * 3 + 0];
        fg[k] = features[g * 3 + 1];
        fb[k] = features[g * 3 + 2];
    }

    // ---- project + window-test + per-wave ballot compaction (keys to LDS) ----
    float4 eA[4], eB[4];
    unsigned long long ekey[4];
    int epos[4];
    int cnt = 0;
#pragma unroll
    for (int k = 0; k < 4; k++) {
        const int g = (k << 8) + t;
        const float q0 = mx[k] * V[0] + my[k] * V[4] + mz[k] * V[8]  + V[12];
        const float q1 = mx[k] * V[1] + my[k] * V[5] + mz[k] * V[9]  + V[13];
        const float q2 = mx[k] * V[2] + my[k] * V[6] + mz[k] * V[10] + V[14];
        const float q3 = mx[k] * V[3] + my[k] * V[7] + mz[k] * V[11] + V[15];
        const float h0 = q0 * P[0] + q1 * P[4] + q2 * P[8]  + q3 * P[12];
        const float h1 = q0 * P[1] + q1 * P[5] + q2 * P[9]  + q3 * P[13];
        const float h3 = q0 * P[3] + q1 * P[7] + q2 * P[11] + q3 * P[15];

        const float inv_w = 1.0f / (h3 + 1e-6f);
        const float m2x = ((h0 * inv_w + 1.0f) * (float)WW - 1.0f) * 0.5f;
        const float m2y = ((h1 * inv_w + 1.0f) * (float)HH - 1.0f) * 0.5f;

        const float s2 = sc[k] * FOCAL_F / q2;
        const float radii = s2 * RADII_MULT_F;
        const float kexp = -0.72134752044448170f / (s2 * s2);  // -0.5*log2(e)/s2sq

        const float rminx = fminf(fmaxf(m2x - radii, 0.0f), (float)(WW - 1));
        const float rminy = fminf(fmaxf(m2y - radii, 0.0f), (float)(HH - 1));
        const float rmaxx = fminf(fmaxf(m2x + radii, 0.0f), (float)(WW - 1));
        const float rmaxy = fminf(fmaxf(m2y + radii, 0.0f), (float)(HH - 1));

        const bool pass = (fminf(rmaxx, u1f) > fmaxf(rminx, u0f)) &&
                          (rminy <= py1f) && (rmaxy >= py0f);
        const unsigned long long m = __ballot(pass);
        epos[k] = -1;
        if (pass) {
            const int off = (w << 8) + cnt + __popcll(m & ((1ull << l) - 1ull));
            epos[k] = off;
            eA[k] = make_float4(m2x, m2y, kexp, op[k]);
            eB[k] = make_float4(fr[k], fg[k], fb[k], q2);
            // monotone float->uint map, gid in low bits = stable argsort
            unsigned int ub = __float_as_uint(q2);
            ub = (ub & 0x80000000u) ? ~ub : (ub | 0x80000000u);
            ekey[k] = ((unsigned long long)ub << 32) | (unsigned int)g;
            s_key[off] = ekey[k];
        }
        cnt += __popcll(m);
    }
    if (l == 0) s_cnt[w] = cnt;
    __syncthreads();

    const int c0 = s_cnt[0], c1 = s_cnt[1], c2 = s_cnt[2], c3 = s_cnt[3];
    const int n = c0 + c1 + c2 + c3;

    // ---- rank my entries: count keys strictly smaller (broadcast scan) ----
    int rk[4] = {0, 0, 0, 0};
#pragma unroll
    for (int s = 0; s < 4; s++) {
        const int cn = (s == 0) ? c0 : (s == 1) ? c1 : (s == 2) ? c2 : c3;
        const int base = s << 8;
        for (int j = 0; j < cn; j++) {
            const unsigned long long k2 = s_key[base + j];
#pragma unroll
            for (int k = 0; k < 4; k++)
                if (epos[k] >= 0 && k2 < ekey[k]) rk[k]++;
        }
    }

    // ---- scatter register-held attrs straight to ranked slots ----
#pragma unroll
    for (int k = 0; k < 4; k++) {
        if (epos[k] >= 0) {
            s_sorted[rk[k]][0] = eA[k];
            s_sorted[rk[k]][1] = eB[k];
        }
    }
    __syncthreads();

    // ---- front-to-back blend: each wave does half of the sorted list ----
    const int h = (n + 1) >> 1;
    const int e0 = half ? h : 0;
    const int e1 = half ? n : h;

    float T = 1.0f, cr = 0.0f, cg = 0.0f, cb = 0.0f, dsum = 0.0f, accsum = 0.0f;
    for (int e = e0; e < e1; e++) {
        const float4 a = s_sorted[e][0];
        const float4 b = s_sorted[e][1];
        const float dx = px - a.x;
        const float dy = py - a.y;
        const float d2 = fmaf(dx, dx, dy * dy);
        const float gw = exp2f(d2 * a.z);
        const float alpha = fminf(gw * a.w, 0.99f);
        const float wgt = alpha * T;
        cr   = fmaf(wgt, b.x, cr);
        cg   = fmaf(wgt, b.y, cg);
        cb   = fmaf(wgt, b.z, cb);
        dsum = fmaf(wgt, b.w, dsum);
        accsum += wgt;
        T = fmaf(-alpha, T, T);              // T *= (1 - alpha)
    }

    // back waves publish partial sums; front waves compose and write out
    if (half == 1) {
        s_part[row][0][l] = cr;
        s_part[row][1][l] = cg;
        s_part[row][2][l] = cb;
        s_part[row][3][l] = dsum;
        s_part[row][4][l] = accsum;
    }
    __syncthreads();

    if (half == 0) {
        cr     = fmaf(T, s_part[row][0][l], cr);
        cg     = fmaf(T, s_part[row][1][l], cg);
        cb     = fmaf(T, s_part[row][2][l], cb);
        dsum   = fmaf(T, s_part[row][3][l], dsum);
        accsum = fmaf(T, s_part[row][4][l], accsum);

        const float bg = 1.0f - accsum;
        cr = fminf(fmaxf(cr + bg, 0.0f), 1.0f);
        cg = fminf(fmaxf(cg + bg, 0.0f), 1.0f);
        cb = fminf(fmaxf(cb + bg, 0.0f), 1.0f);

        const int pix = pyi * WW + pxi;
        out[pix * 3 + 0] = cr;
        out[pix * 3 + 1] = cg;
        out[pix * 3 + 2] = cb;
        out[WW * HH * 3 + pix] = dsum;
        out[WW * HH * 4 + pix] = accsum;
    }
}

extern "C" void kernel_launch(void* const* d_in, const int* in_sizes, int n_in,
                              void* d_out, int out_size, void* d_ws, size_t ws_size,
                              hipStream_t stream) {
    const float* means3d  = (const float*)d_in[0];
    const float* opacity  = (const float*)d_in[1];
    const float* scale3d  = (const float*)d_in[2];
    const float* features = (const float*)d_in[3];
    const float* viewm    = (const float*)d_in[4];
    const float* projm    = (const float*)d_in[5];
    float* out = (float*)d_out;

    fused_render_kernel<<<512, 256, 0, stream>>>(means3d, opacity, scale3d,
                                                 features, viewm, projm, out);
}